// Round 13
// baseline (449.897 us; speedup 1.0000x reference)
//
#include <hip/hip_runtime.h>

typedef unsigned short u16;
typedef unsigned int   u32;
typedef __bf16 bf16x8 __attribute__((ext_vector_type(8)));
typedef float  f32x4  __attribute__((ext_vector_type(4)));

#define EPS 1e-5f
#define BSHIFT 9               // 512 node ids per bucket

__device__ __forceinline__ float b2f(u16 u){ union{u32 i; float f;} v; v.i=((u32)u)<<16; return v.f; }
__device__ __forceinline__ u16 f2b(float f){
  u32 x = __float_as_uint(f);
  u32 r = x + 0x7fffu + ((x>>16)&1u);   // round-to-nearest-even
  return (u16)(r>>16);
}

// ---- GEMM body (used by fused k_gemm2 only). Frozen at r11 config.
// Ledger of refuted GEMM theories: forced launch_bounds -> spill (r2/r4);
// fewer atomics -> slower at VGPR cliff (r7); more blocks/CU -> slower (r8);
// traffic halved -> ~no change (r11). ~74-83us is structural; r12 showed
// +-10us run-to-run variance on identical code.
template<int K, bool RELU, bool HASBIAS, bool AF32, bool POOL>
__device__ __forceinline__ void gemm_body(const void* __restrict__ Av,
                                          const u16* __restrict__ BhiT,
                                          const u16* __restrict__ BloT,
                                          const float* __restrict__ bias,
                                          u16* __restrict__ C,
                                          float* __restrict__ stats,
                                          const int* __restrict__ batch,
                                          float* __restrict__ P, int M,
                                          int bid, int halfg)
{
  constexpr int KM = K / 8;                 // 8-elem (16B) blocks per row
  constexpr int KR = K / 32;                // bf16x8 fragments per lane
  constexpr int GCAP = 8;                   // LDS graph-window capacity
  extern __shared__ char smem[];
  u16* lds    = (u16*)smem;                 // [hi|lo][64 cols][K swizzled]
  float* sred = (float*)(smem + (size_t)2 * 64 * K * 2);
  float* qred = sred + 64;
  u16*  sbatch = (u16*)(qred + 64);         // [1024] block's batch slice (POOL)
  float* Pacc  = (float*)(sbatch + 1024);   // [GCAP*64] LDS P window (POOL)
  const int tid = threadIdx.x;
  const int ch = (bid >= halfg) ? 1 : 0;    // column half: cols ch*64..+63
  const int t0 = bid - ch * halfg;          // pair (b, b+halfg): same XCD
  for (int i = tid; i < 64 * KM; i += 256) {
    const int n = i / KM, kb = i % KM;
    const int kb2 = kb ^ (n & (KM - 1));
    const int gsrc = ((ch * 64 + n) * KM + kb) * 8;
    *(uint4*)(&lds[(n * KM + kb2) * 8])          = *(const uint4*)(BhiT + gsrc);
    *(uint4*)(&lds[64 * K + (n * KM + kb2) * 8]) = *(const uint4*)(BloT + gsrc);
  }
  if (tid < 64) { sred[tid] = 0.f; qred[tid] = 0.f; }
  const int nmt = (M + 127) >> 7;           // 128-row macro tiles (M % 64 == 0)
  int mt_begin, mt_end, mt_step, rlo = 0;
  if (POOL) {
    const int qt = nmt / halfg, rm = nmt % halfg;
    mt_begin = (t0 < rm) ? t0 * (qt + 1) : rm * (qt + 1) + (t0 - rm) * qt;
    mt_end   = mt_begin + ((t0 < rm) ? qt + 1 : qt);
    mt_step  = 1;
    rlo = mt_begin << 7;
    const int rcnt = min(mt_end << 7, M) - rlo;   // <= 1024 (max 7 tiles/block)
    for (int i = tid; i < rcnt; i += 256) sbatch[i] = (u16)batch[rlo + i];
    for (int i = tid; i < GCAP * 64; i += 256) Pacc[i] = 0.f;
  } else {
    mt_begin = t0; mt_end = nmt; mt_step = halfg;
  }
  __syncthreads();
  const int g_lo = POOL ? (int)sbatch[0] : 0;     // wave-uniform broadcast read
  const int wid = tid >> 6, lane = tid & 63, q = lane >> 4, r16 = lane & 15;
  float ls[4], lq[4];
#pragma unroll
  for (int nb = 0; nb < 4; nb++) { ls[nb] = 0.f; lq[nb] = 0.f; }
  float bv[4];
#pragma unroll
  for (int nb = 0; nb < 4; nb++) bv[nb] = HASBIAS ? bias[ch * 64 + nb * 16 + r16] : 0.f;

  for (int mt = mt_begin; mt < mt_end; mt += mt_step) {
    const int row0 = mt << 7;               // rt=0 rows always valid
    const bool ok1 = (row0 + 64) < M;       // rt=1 rows row0+64..127

    bf16x8 av[2][KR];
    if (AF32) {
      const float* Af = (const float*)Av + (size_t)(row0 + (wid << 4) + r16) * K + q * 8;
#pragma unroll
      for (int kk = 0; kk < KR; kk++) {
        f32x4 x0 = *(const f32x4*)(Af + kk * 32);
        f32x4 x1 = *(const f32x4*)(Af + kk * 32 + 4);
#pragma unroll
        for (int j = 0; j < 4; j++) { av[0][kk][j] = (__bf16)x0[j]; av[0][kk][4 + j] = (__bf16)x1[j]; }
      }
      if (ok1) {
        const float* Ag = Af + (size_t)64 * K;
#pragma unroll
        for (int kk = 0; kk < KR; kk++) {
          f32x4 x0 = *(const f32x4*)(Ag + kk * 32);
          f32x4 x1 = *(const f32x4*)(Ag + kk * 32 + 4);
#pragma unroll
          for (int j = 0; j < 4; j++) { av[1][kk][j] = (__bf16)x0[j]; av[1][kk][4 + j] = (__bf16)x1[j]; }
        }
      }
    } else {
      const u16* Ab = (const u16*)Av + (size_t)(row0 + (wid << 4) + r16) * K + q * 8;
#pragma unroll
      for (int kk = 0; kk < KR; kk++) av[0][kk] = *(const bf16x8*)(Ab + kk * 32);
      if (ok1) {
#pragma unroll
        for (int kk = 0; kk < KR; kk++) av[1][kk] = *(const bf16x8*)(Ab + (size_t)64 * K + kk * 32);
      }
    }

    f32x4 acc[2][4];
#pragma unroll
    for (int rt = 0; rt < 2; rt++)
#pragma unroll
      for (int nb = 0; nb < 4; nb++) acc[rt][nb] = (f32x4){0.f, 0.f, 0.f, 0.f};
#pragma unroll
    for (int kk = 0; kk < KR; kk++) {
#pragma unroll
      for (int nb = 0; nb < 4; nb++) {
        const int n = nb * 16 + r16;
        const int kb2 = (kk * 4 + q) ^ (n & (KM - 1));
        const bf16x8 bh = *(const bf16x8*)(&lds[(n * KM + kb2) * 8]);
        const bf16x8 bl = *(const bf16x8*)(&lds[64 * K + (n * KM + kb2) * 8]);
        acc[0][nb] = __builtin_amdgcn_mfma_f32_16x16x32_bf16(av[0][kk], bh, acc[0][nb], 0, 0, 0);
        acc[0][nb] = __builtin_amdgcn_mfma_f32_16x16x32_bf16(av[0][kk], bl, acc[0][nb], 0, 0, 0);
        if (ok1) {
          acc[1][nb] = __builtin_amdgcn_mfma_f32_16x16x32_bf16(av[1][kk], bh, acc[1][nb], 0, 0, 0);
          acc[1][nb] = __builtin_amdgcn_mfma_f32_16x16x32_bf16(av[1][kk], bl, acc[1][nb], 0, 0, 0);
        }
      }
    }

#pragma unroll
    for (int rt = 0; rt < 2; rt++) {
      if (rt && !ok1) continue;
      const int rbase = row0 + rt * 64 + (wid << 4) + (q << 2);
#pragma unroll
      for (int nb = 0; nb < 4; nb++) {
        const int col = ch * 64 + nb * 16 + r16;
#pragma unroll
        for (int r = 0; r < 4; r++) {
          float v = acc[rt][nb][r] + bv[nb];
          if (RELU) v = fmaxf(v, 0.f);
          ls[nb] += v; lq[nb] += v * v;
          if (!POOL) C[(size_t)(rbase + r) * 128 + col] = f2b(v);
          else acc[rt][nb][r] = v;
        }
      }
      if (POOL) {
        int bg[4];
#pragma unroll
        for (int r = 0; r < 4; r++) bg[r] = (int)sbatch[rbase - rlo + r];   // LDS, no vmcnt
        const int g0 = __shfl(bg[0], 0, 64);    // batch[first row of wave tile]
        const int g1 = __shfl(bg[3], 48, 64);   // batch[last row of wave tile]
        for (int g = g0; g <= g1; ++g) {        // wave-uniform, almost always 1 iter
#pragma unroll
          for (int nb = 0; nb < 4; nb++) {
            float sv = 0.f;
#pragma unroll
            for (int r = 0; r < 4; r++) sv += (bg[r] == g) ? acc[rt][nb][r] : 0.f;
            sv += __shfl_xor(sv, 16, 64);       // sum the 4 q-groups (16 rows)
            sv += __shfl_xor(sv, 32, 64);
            if (q == 0) {
              const int gi = g - g_lo;          // wave-uniform branch
              if ((unsigned)gi < GCAP) atomicAdd(&Pacc[gi * 64 + nb * 16 + r16], sv);
              else atomicAdd(&P[g * 128 + ch * 64 + nb * 16 + r16], sv);
            }
          }
        }
      }
    }
  }
#pragma unroll
  for (int nb = 0; nb < 4; nb++) {
    atomicAdd(&sred[nb * 16 + r16], ls[nb]);
    atomicAdd(&qred[nb * 16 + r16], lq[nb]);
  }
  __syncthreads();
  if (tid < 64) {
    atomicAdd(&stats[ch * 64 + tid], sred[tid]);
    atomicAdd(&stats[128 + ch * 64 + tid], qred[tid]);
  }
  if (POOL) {
    // one flush per block; zero entries skipped (RELU values nonneg -> exact)
    for (int i = tid; i < GCAP * 64; i += 256) {
      const float v = Pacc[i];
      if (v != 0.f) atomicAdd(&P[(g_lo + (i >> 6)) * 128 + ch * 64 + (i & 63)], v);
    }
  }
}

// ---- fused dispatch: blocks [0,g1blk) = K=128 POOL GEMM (h0 -> P1),
//      blocks [g1blk, g1blk+g2blk) = K=32 POOL GEMM (act -> P2). ----
__global__ __launch_bounds__(256) void k_gemm2(const void* __restrict__ A1,
                                               const u16* __restrict__ B1hi,
                                               const u16* __restrict__ B1lo,
                                               const float* __restrict__ bias1,
                                               float* __restrict__ stats1,
                                               float* __restrict__ P1,
                                               const void* __restrict__ A2,
                                               const u16* __restrict__ B2hi,
                                               const u16* __restrict__ B2lo,
                                               const float* __restrict__ bias2,
                                               float* __restrict__ stats2,
                                               float* __restrict__ P2,
                                               const int* __restrict__ batch,
                                               int M, int g1blk, int g2blk)
{
  if ((int)blockIdx.x < g1blk)
    gemm_body<128, true, true, false, true>(A1, B1hi, B1lo, bias1, nullptr, stats1,
                                            batch, P1, M, blockIdx.x, g1blk >> 1);
  else
    gemm_body<32, true, true, true, true>(A2, B2hi, B2lo, bias2, nullptr, stats2,
                                          batch, P2, M, blockIdx.x - g1blk, g2blk >> 1);
}

// ---- FUSED aggregation + K=64 GEMM: one 512-thr block per 128-row tile.
// Phase 1: 8 waves aggregate 16 nodes each (k_agg's proven gather scheme,
// 2 nodes/wave-iteration) into an LDS A-tile (stride 72 u16: 2-way max bank
// aliasing = free). Phase 2: hi/lo MFMA vs LDS-staged Wg, epilogue h0+stats0.
// Kills the 51MB aggx round-trip + one dispatch. Tail block (64 rows): waves
// 4-7 guarded by ok1 (no barriers inside guards).
__global__ __launch_bounds__(512) void k_aggemm(const u16* __restrict__ y,
                                                const int* __restrict__ offsets,
                                                const int* __restrict__ elist,
                                                const float* __restrict__ dinv,
                                                const u16* __restrict__ WhiT,
                                                const u16* __restrict__ WloT,
                                                const float* __restrict__ bias,
                                                u16* __restrict__ C,
                                                float* __restrict__ stats, int M)
{
  __shared__ u16 wlds[2 * 128 * 64];        // hi|lo [128 cols][64 k swizzled] 32KB
  __shared__ u16 atile[128 * 72];           // A rows, stride 72 u16 (144B) 18KB
  __shared__ float sred[128], qred[128];
  const int tid = threadIdx.x;
  for (int i = tid; i < 128 * 8; i += 512) {
    const int n = i >> 3, kb = i & 7;
    const int kb2 = kb ^ (n & 7);
    *(uint4*)(&wlds[(n * 8 + kb2) * 8])            = *(const uint4*)(WhiT + i * 8);
    *(uint4*)(&wlds[128 * 64 + (n * 8 + kb2) * 8]) = *(const uint4*)(WloT + i * 8);
  }
  if (tid < 128) { sred[tid] = 0.f; qred[tid] = 0.f; }

  const int rowb = blockIdx.x << 7;         // 128 rows/block; M % 64 == 0
  const bool ok1 = (rowb + 64) < M;         // waves 4-7 valid?
  const int wid = tid >> 6, lane = tid & 63;
  const int half = lane >> 5, l32 = lane & 31;
  const int g4 = l32 >> 3, sub = lane & 7;

  // ---- phase 1: aggregation (wave wid -> local rows wid*16..+15, 8 pairs) ----
  if (wid < 4 || ok1) {
    for (int pr = 0; pr < 8; pr++) {
      const int node = rowb + (wid << 4) + pr * 2 + half;
      const int s0 = offsets[node], s1 = offsets[node + 1];
      const int mydeg = s1 - s0;
      const int degA = __shfl(mydeg, 0, 64);
      const int degB = __shfl(mydeg, 32, 64);
      const int degmax = max(degA, degB);
      float a[8];
#pragma unroll
      for (int t = 0; t < 8; t++) a[t] = 0.f;
      for (int base = 0; base < degmax; base += 32) {
        const int m = mydeg - base;
        const int ev = (base + l32 < mydeg) ? elist[s0 + base + l32] : 0;
        const int iters = (min(32, degmax - base) + 3) >> 2;   // wave-uniform
        for (int it = 0; it < iters; it++) {
          const int j = it * 4 + g4;
          const int idx = __shfl(ev, half * 32 + j, 64);       // all lanes active
          if (j < m) {
            const uint4 v = *(const uint4*)(y + (size_t)idx * 64 + sub * 8);
            const u32 w[4] = {v.x, v.y, v.z, v.w};
#pragma unroll
            for (int t = 0; t < 4; t++) {
              a[2 * t]     += b2f((u16)w[t]);
              a[2 * t + 1] += b2f((u16)(w[t] >> 16));
            }
          }
        }
      }
#pragma unroll
      for (int t = 0; t < 8; t++) {
        a[t] += __shfl_xor(a[t], 8, 64);
        a[t] += __shfl_xor(a[t], 16, 64);
      }
      if (g4 == 0) {
        const float di = dinv[node];
        u16 o[8];
#pragma unroll
        for (int t = 0; t < 8; t++) o[t] = f2b(a[t] * di);
        const int lrow = (wid << 4) + pr * 2 + half;
        *(uint4*)(&atile[lrow * 72 + sub * 8]) = *(uint4*)o;
      }
    }
  }
  __syncthreads();

  // ---- phase 2: MFMA (wave wid -> output rows wid*16..+15, all 128 cols) ----
  const int q = lane >> 4, r16 = lane & 15;
  float ls[8], lq[8];
#pragma unroll
  for (int nb = 0; nb < 8; nb++) { ls[nb] = 0.f; lq[nb] = 0.f; }
  if (wid < 4 || ok1) {
    bf16x8 av[2];
#pragma unroll
    for (int kk = 0; kk < 2; kk++)
      av[kk] = *(const bf16x8*)(&atile[((wid << 4) + r16) * 72 + kk * 32 + q * 8]);
    f32x4 acc[8];
#pragma unroll
    for (int nb = 0; nb < 8; nb++) acc[nb] = (f32x4){0.f, 0.f, 0.f, 0.f};
#pragma unroll
    for (int kk = 0; kk < 2; kk++) {
#pragma unroll
      for (int nb = 0; nb < 8; nb++) {
        const int n = nb * 16 + r16;
        const int kb2 = (kk * 4 + q) ^ (n & 7);
        const bf16x8 bh = *(const bf16x8*)(&wlds[(n * 8 + kb2) * 8]);
        const bf16x8 bl = *(const bf16x8*)(&wlds[128 * 64 + (n * 8 + kb2) * 8]);
        acc[nb] = __builtin_amdgcn_mfma_f32_16x16x32_bf16(av[kk], bh, acc[nb], 0, 0, 0);
        acc[nb] = __builtin_amdgcn_mfma_f32_16x16x32_bf16(av[kk], bl, acc[nb], 0, 0, 0);
      }
    }
    const int rbase = rowb + (wid << 4) + (q << 2);
#pragma unroll
    for (int nb = 0; nb < 8; nb++) {
      const int col = nb * 16 + r16;
      const float bv = bias[col];
#pragma unroll
      for (int r = 0; r < 4; r++) {
        float v = acc[nb][r] + bv;
        v = fmaxf(v, 0.f);
        ls[nb] += v; lq[nb] += v * v;
        C[(size_t)(rbase + r) * 128 + col] = f2b(v);
      }
      atomicAdd(&sred[col], ls[nb]);
      atomicAdd(&qred[col], lq[nb]);
    }
  }
  __syncthreads();
  if (tid < 128) {
    atomicAdd(&stats[tid], sred[tid]);
    atomicAdd(&stats[128 + tid], qred[tid]);
  }
}

// ---- prep0: blocks [0,NZ) zero scratch; [NZ,NZ+48) split Wg/W2 hi/lo T; rest: bounds ----
__global__ void k_prep0(const float* __restrict__ Wg, const float* __restrict__ W2,
                        u16* __restrict__ WghiT, u16* __restrict__ WgloT,
                        u16* __restrict__ W2hiT, u16* __restrict__ W2loT,
                        const int* __restrict__ batch, int* __restrict__ gofs,
                        int* __restrict__ zbase, int zwords, int NZ, int N, int B)
{
  const int bid = blockIdx.x, t = threadIdx.x;
  if (bid < NZ) {
    const int i = bid * 2048 + t * 8;       // zwords padded to multiple of 8
    if (i < zwords) {
      *(int4*)(zbase + i)     = make_int4(0, 0, 0, 0);
      *(int4*)(zbase + i + 4) = make_int4(0, 0, 0, 0);
    }
  } else if (bid < NZ + 48) {
    const int i = (bid - NZ) * 256 + t;
    if (i < 64 * 128) {
      int k = i >> 7, n = i & 127;
      float w = Wg[i]; u16 h = f2b(w);
      WghiT[n * 64 + k] = h; WgloT[n * 64 + k] = f2b(w - b2f(h));
    } else if (i < 64 * 128 + 32 * 128) {
      int j = i - 64 * 128;
      int k = j >> 7, n = j & 127;
      float w = W2[j]; u16 h = f2b(w);
      W2hiT[n * 32 + k] = h; W2loT[n * 32 + k] = f2b(w - b2f(h));
    }
  } else {
    const int i = (bid - NZ - 48) * 256 + t;
    if (i == 0) { for (int g = 0; g <= batch[0]; g++) gofs[g] = 0; }
    if (i == N - 1) { for (int g = batch[N - 1] + 1; g <= B; g++) gofs[g] = N; }
    if (i < N - 1) {
      const int b0 = batch[i], b1 = batch[i + 1];
      for (int g = b0 + 1; g <= b1; g++) gofs[g] = i + 1;
    }
  }
}

// ========== binned edge partition ==========
__global__ __launch_bounds__(256) void k_bincnt(const int* __restrict__ dst, int* __restrict__ btot,
                                                int E, int NB)
{
  extern __shared__ int hist[];
  const int tid = threadIdx.x;
  for (int i = tid; i < NB; i += 256) hist[i] = 0;
  __syncthreads();
  const int chunk = (E + gridDim.x - 1) / gridDim.x;
  const int start = blockIdx.x * chunk;
  const int end = min(start + chunk, E);
  for (int e = start + tid; e < end; e += 256) atomicAdd(&hist[((u32)dst[e]) >> BSHIFT], 1);
  __syncthreads();
  for (int i = tid; i < NB; i += 256) if (hist[i]) atomicAdd(&btot[i], hist[i]);
}

// re-read edges; INLINE exclusive scan of btot (no k_exscan dispatch); block 0
// materializes bbase for k_bucket; reserve per-(block,bucket) ranges; stream pairs.
__global__ __launch_bounds__(256) void k_bin(const int* __restrict__ src, const int* __restrict__ dst,
                                             const int* __restrict__ btot, int* __restrict__ bcur,
                                             int* __restrict__ bbase_out,
                                             uint2* __restrict__ pairs, int E, int NB)
{
  extern __shared__ int lds[];
  int* sb    = lds;              // [NB] scanned bucket bases
  int* hist  = lds + NB;         // [NB]
  int* wbase = lds + 2 * NB;     // [NB]
  int* sscan = lds + 3 * NB;     // [256]
  const int tid = threadIdx.x;
  const int per = (NB + 255) / 256;      // 2 for NB~391
  int loc[4]; int sum = 0;
  for (int j = 0; j < per; j++) { int idx = tid * per + j; int v = (idx < NB) ? btot[idx] : 0; loc[j] = sum; sum += v; }
  sscan[tid] = sum; __syncthreads();
  for (int o = 1; o < 256; o <<= 1) {
    int x = (tid >= o) ? sscan[tid - o] : 0;
    __syncthreads();
    sscan[tid] += x;
    __syncthreads();
  }
  const int ex = sscan[tid] - sum;
  for (int j = 0; j < per; j++) {
    int idx = tid * per + j;
    if (idx < NB) {
      sb[idx] = ex + loc[j];
      if (blockIdx.x == 0) bbase_out[idx] = ex + loc[j];
    }
  }
  if (blockIdx.x == 0 && tid == 255) bbase_out[NB] = sscan[255];
  for (int i = tid; i < NB; i += 256) hist[i] = 0;
  __syncthreads();
  const int chunk = (E + gridDim.x - 1) / gridDim.x;
  const int start = blockIdx.x * chunk;
  const int end = min(start + chunk, E);
  for (int e = start + tid; e < end; e += 256) atomicAdd(&hist[((u32)dst[e]) >> BSHIFT], 1);
  __syncthreads();
  for (int i = tid; i < NB; i += 256) {
    int c = hist[i];
    wbase[i] = c ? sb[i] + atomicAdd(&bcur[i], c) : 0;
    hist[i] = 0;
  }
  __syncthreads();
  for (int e = start + tid; e < end; e += 256) {
    const int d = dst[e];
    const int b = ((u32)d) >> BSHIFT;
    const int o = atomicAdd(&hist[b], 1);
    pairs[wbase[b] + o] = make_uint2((u32)d, (u32)src[e]);
  }
}

// ---- per-bucket CSR build + fused x->y cast (512 threads, 1 node/thread) ----
__global__ __launch_bounds__(512) void k_bucket(const uint2* __restrict__ pairs,
                                                const int* __restrict__ bbase,
                                                const float* __restrict__ x,
                                                int* __restrict__ offsets, float* __restrict__ dinv,
                                                int* __restrict__ elist, u16* __restrict__ y,
                                                int N, int NB, int Etot)
{
  __shared__ int hist[512];
  __shared__ int scn[512];
  __shared__ int lcur[512];
  __shared__ float sdinv[512];
  const int b = blockIdx.x, t = threadIdx.x;      // t in [0,512)
  const int nbase = b << BSHIFT;
  const int nn = min(1 << BSHIFT, N - nbase);
  hist[t] = 0;
  __syncthreads();
  const int p0 = bbase[b], p1 = bbase[b + 1];
  for (int p = p0 + t; p < p1; p += 512) atomicAdd(&hist[pairs[p].x - nbase], 1);
  __syncthreads();
  const int h = hist[t];
  scn[t] = h; __syncthreads();
  for (int o = 1; o < 512; o <<= 1) {
    int xx = (t >= o) ? scn[t - o] : 0;
    __syncthreads();
    scn[t] += xx;
    __syncthreads();
  }
  const int ex = scn[t] - h;       // edges in this bucket before node t
  if (t < nn) {
    const int i = nbase + t;
    const int off = p0 + ex + i;   // +i: one self-loop slot per preceding node
    const float d = rsqrtf((float)(h + 1));
    offsets[i] = off; elist[off] = i; lcur[t] = off + 1;
    dinv[i] = d; sdinv[t] = d;
  }
  if (b == NB - 1 && t == 0) offsets[N] = Etot;
  __syncthreads();
  for (int p = p0 + t; p < p1; p += 512) {
    const uint2 pr = pairs[p];
    const int pos = atomicAdd(&lcur[pr.x - nbase], 1);
    elist[pos] = (int)pr.y;
  }
  const size_t ebase = (size_t)nbase * 64;
  const int total = nn * 64;
  for (int i = t * 8; i < total; i += 512 * 8) {
    const float d = sdinv[i >> 6];
    f32x4 a = *(const f32x4*)(x + ebase + i);
    f32x4 c = *(const f32x4*)(x + ebase + i + 4);
    u16 o[8];
#pragma unroll
    for (int j = 0; j < 4; j++) { o[j] = f2b(a[j] * d); o[4 + j] = f2b(c[j] * d); }
    *(uint4*)(y + ebase + i) = *(uint4*)o;
  }
}

// ---- fold BN0 into W1 (16 blocks x 8 k-rows): W1p = diag(a0)W1 hi/lo T, b1p = c0@W1+b1 ----
__global__ void k_prep1(const float* __restrict__ stats0, const float* __restrict__ W1,
                        const float* __restrict__ b1, const float* __restrict__ g0,
                        const float* __restrict__ be0, u16* __restrict__ W1hiT,
                        u16* __restrict__ W1loT, float* __restrict__ b1p, float n)
{
  __shared__ float A[8], Csh[8];
  const int t = threadIdx.x;  // 128 threads
  if (t < 8) {
    const int k = blockIdx.x * 8 + t;
    const float mu = stats0[k] / n;
    const float var = fmaxf(stats0[128 + k] / n - mu * mu, 0.f);
    const float a = g0[k] * rsqrtf(var + EPS);
    A[t] = a; Csh[t] = be0[k] - mu * a;
  }
  __syncthreads();
  float acc = (blockIdx.x == 0) ? b1[t] : 0.f;
#pragma unroll
  for (int kk = 0; kk < 8; kk++) {
    const int k = blockIdx.x * 8 + kk;
    const float w0 = W1[k * 128 + t];
    acc += Csh[kk] * w0;
    const float w = A[kk] * w0;
    const u16 h = f2b(w);
    W1hiT[t * 128 + k] = h;
    W1loT[t * 128 + k] = f2b(w - b2f(h));
  }
  atomicAdd(&b1p[t], acc);
}

// ---- merged BN1/BN2+W3 fold + per-graph head ----
__global__ void k_out3(const float* __restrict__ P1, const float* __restrict__ P2,
                       const int* __restrict__ gofs,
                       const float* __restrict__ stats1, const float* __restrict__ stats2,
                       const float* __restrict__ g1, const float* __restrict__ be1,
                       const float* __restrict__ g2, const float* __restrict__ be2,
                       const float* __restrict__ W3, const float* __restrict__ b3,
                       float* __restrict__ out, int B, float n)
{
  __shared__ float w1s[128], w2s[128], red[256], cS[2];
  const int t = threadIdx.x;  // 256 threads
  float c, wv;
  if (t < 128) {
    const float mu = stats1[t] / n;
    const float var = fmaxf(stats1[128 + t] / n - mu * mu, 0.f);
    const float a = g1[t] * rsqrtf(var + EPS);
    c = be1[t] - mu * a;
    wv = W3[t];
    w1s[t] = a * wv;
  } else {
    const int f = t - 128;
    const float mu = stats2[f] / n;
    const float var = fmaxf(stats2[128 + f] / n - mu * mu, 0.f);
    const float a = g2[f] * rsqrtf(var + EPS);
    c = be2[f] - mu * a;
    wv = W3[t];
    w2s[f] = a * wv;
  }
  red[t] = c * wv; __syncthreads();
  for (int o = 128; o; o >>= 1) { if (t < o) red[t] += red[t + o]; __syncthreads(); }
  if (t == 0) { cS[0] = red[0] + b3[0]; cS[1] = b3[0]; }
  __syncthreads();
  const int lane = t & 63;
  const int g = (blockIdx.x * 256 + t) >> 6;
  if (g >= B) return;
  const int cnt = gofs[g + 1] - gofs[g];
  const int k = 2 * lane;
  float d = P1[g * 128 + k] * w1s[k] + P1[g * 128 + k + 1] * w1s[k + 1]
          + P2[g * 128 + k] * w2s[k] + P2[g * 128 + k + 1] * w2s[k + 1];
#pragma unroll
  for (int o = 1; o < 64; o <<= 1) d += __shfl_xor(d, o, 64);
  if (lane == 0) out[g] = (cnt > 0) ? d / (float)cnt + cS[0] : cS[1];
}

extern "C" void kernel_launch(void* const* d_in, const int* in_sizes, int n_in,
                              void* d_out, int out_size, void* d_ws, size_t ws_size,
                              hipStream_t stream)
{
  const float* x    = (const float*)d_in[0];
  const float* act  = (const float*)d_in[1];
  const float* Wg   = (const float*)d_in[2];
  const float* bg   = (const float*)d_in[3];
  const float* g0   = (const float*)d_in[4];
  const float* be0  = (const float*)d_in[5];
  const float* W1   = (const float*)d_in[6];
  const float* b1   = (const float*)d_in[7];
  const float* g1   = (const float*)d_in[8];
  const float* be1  = (const float*)d_in[9];
  const float* W2   = (const float*)d_in[10];
  const float* b2   = (const float*)d_in[11];
  const float* g2   = (const float*)d_in[12];
  const float* be2  = (const float*)d_in[13];
  const float* W3   = (const float*)d_in[14];
  const float* b3   = (const float*)d_in[15];
  const int* eidx   = (const int*)d_in[16];
  const int* batch  = (const int*)d_in[17];

  const int N = in_sizes[17];          // 200000
  const int E = in_sizes[16] / 2;      // 1600000
  const int B = out_size;              // 1000
  const int* src = eidx;
  const int* dst = eidx + E;
  const int NB = (N + (1 << BSHIFT) - 1) >> BSHIFT;   // ~391 buckets

  char* ws = (char*)d_ws;
  size_t off = 0;
  auto alloc = [&](size_t bytes) -> char* {
    off = (off + 255) & ~(size_t)255;
    char* p = ws + off; off += bytes; return p;
  };

  u16* bufA = (u16*)alloc((size_t)N * 128 * 2);   // h0
  u16* xb   = (u16*)alloc((size_t)N * 64 * 2);    // y (premult bf16 x)

  int zwords = 768 + 128 + 2 * NB + 2 * 128 * B;  // stats+b1p+bins + P1+P2
  zwords = (zwords + 7) & ~7;                     // pad for int4-pair zeroing
  char* zbase   = alloc((size_t)zwords * 4);
  float* stats0 = (float*)zbase;
  float* stats1 = stats0 + 256;
  float* stats2 = stats1 + 256;
  float* b1p    = stats2 + 256;
  int*   btot   = (int*)(b1p + 128);
  int*   bcur   = btot + NB;
  float* P1     = (float*)(bcur + NB);            // [B,128] graph sums of h1
  float* P2     = P1 + 128 * B;                   // [B,128] graph sums of h2

  int*   offsets = (int*)alloc((size_t)(N + 1) * 4);
  float* dinv    = (float*)alloc((size_t)N * 4);
  int*   elist   = (int*)alloc((size_t)(E + N) * 4);
  uint2* pairs   = (uint2*)alloc((size_t)E * 8);
  int*   bbase   = (int*)alloc((size_t)(NB + 1) * 4);
  int*   gofs    = (int*)alloc((size_t)(B + 1) * 4);
  u16*   WghiT   = (u16*)alloc(128 * 64 * 2);
  u16*   WgloT   = (u16*)alloc(128 * 64 * 2);
  u16*   W1hiT   = (u16*)alloc(128 * 128 * 2);
  u16*   W1loT   = (u16*)alloc(128 * 128 * 2);
  u16*   W2hiT   = (u16*)alloc(128 * 32 * 2);
  u16*   W2loT   = (u16*)alloc(128 * 32 * 2);

  u16* h0 = bufA;

  // dynamic-LDS: B tiles (2*64*K u16 * 2) + sred/qred 512B + sbatch 2KB + Pacc 2KB
  const int smem128 = 2 * 64 * 128 * 2 + 512 + 2048 + 2048;   // 37376 B (fused max)
  const int smembin = (3 * NB + 256) * 4;                     // k_bin scan+hists

  // prep0: zero scratch (parallel, ~1 MB) + weight split + graph bounds
  const int NZ = (zwords + 2047) / 2048;          // 256 thr x 8 words per block
  const int nbounds = (N + 255) / 256;
  k_prep0<<<NZ + 48 + nbounds, 256, 0, stream>>>(Wg, W2, WghiT, WgloT, W2hiT, W2loT,
                                                 batch, gofs, (int*)zbase, zwords, NZ, N, B);
  // binned edge partition (exscan folded into k_bin) -> per-bucket CSR + cast
  k_bincnt<<<512, 256, NB * 4, stream>>>(dst, btot, E, NB);
  k_bin<<<512, 256, smembin, stream>>>(src, dst, btot, bcur, bbase, pairs, E, NB);
  k_bucket<<<NB, 512, 0, stream>>>(pairs, bbase, x, offsets, dinv, elist, xb, N, NB, E + N);
  // FUSED aggregation + K=64 GEMM -> h0 (+stats0); aggx never materialized
  k_aggemm<<<(N + 127) / 128, 512, 0, stream>>>(xb, offsets, elist, dinv,
                                                WghiT, WgloT, bg, h0, stats0, N);
  // fold BN0 into W1
  k_prep1<<<16, 128, 0, stream>>>(stats0, W1, b1, g0, be0, W1hiT, W1loT, b1p, (float)N);
  // FUSED: h1-GEMM (K=128, h0 -> P1) overlapped with h2-GEMM (K=32, act -> P2)
  k_gemm2<<<768 + 512, 256, smem128, stream>>>(h0, W1hiT, W1loT, b1p, stats1, P1,
                                               act, W2hiT, W2loT, b2, stats2, P2,
                                               batch, N, 768, 512);
  // merged BN1/BN2+W3 fold + per-graph head
  k_out3<<<(B * 64 + 255) / 256, 256, 0, stream>>>(P1, P2, gofs, stats1, stats2,
                                                   g1, be1, g2, be2, W3, b3,
                                                   (float*)d_out, B, (float)N);
}

// Round 14
// 365.435 us; speedup vs baseline: 1.2311x; 1.2311x over previous
//
#include <hip/hip_runtime.h>

typedef unsigned short u16;
typedef unsigned int   u32;
typedef __bf16 bf16x8 __attribute__((ext_vector_type(8)));
typedef float  f32x4  __attribute__((ext_vector_type(4)));

#define EPS 1e-5f
#define BSHIFT 9               // 512 node ids per bucket

__device__ __forceinline__ float b2f(u16 u){ union{u32 i; float f;} v; v.i=((u32)u)<<16; return v.f; }
__device__ __forceinline__ u16 f2b(float f){
  u32 x = __float_as_uint(f);
  u32 r = x + 0x7fffu + ((x>>16)&1u);   // round-to-nearest-even
  return (u16)(r>>16);
}

// ---- GEMM body: REVERT to v11 (measured best, 362.3us e2e). Ledger of refuted
// theories: forced launch_bounds -> spill (r2/r4); fewer atomics -> slower at
// VGPR cliff (r7); more blocks/CU -> slower, FETCH-correlated (r8); traffic
// halved -> ~no change (r11); agg+gemm fusion -> barrier converts avg gather
// latency to worst-case, 171us (r13). r12 pre-chain tweaks neutral (+-10us noise).
template<int K, bool RELU, bool HASBIAS, bool AF32, bool POOL>
__device__ __forceinline__ void gemm_body(const void* __restrict__ Av,
                                          const u16* __restrict__ BhiT,
                                          const u16* __restrict__ BloT,
                                          const float* __restrict__ bias,
                                          u16* __restrict__ C,
                                          float* __restrict__ stats,
                                          const int* __restrict__ batch,
                                          float* __restrict__ P, int M,
                                          int bid, int halfg)
{
  constexpr int KM = K / 8;                 // 8-elem (16B) blocks per row
  constexpr int KR = K / 32;                // bf16x8 fragments per lane
  constexpr int GCAP = 8;                   // LDS graph-window capacity
  extern __shared__ char smem[];
  u16* lds    = (u16*)smem;                 // [hi|lo][64 cols][K swizzled]
  float* sred = (float*)(smem + (size_t)2 * 64 * K * 2);
  float* qred = sred + 64;
  u16*  sbatch = (u16*)(qred + 64);         // [1024] block's batch slice (POOL)
  float* Pacc  = (float*)(sbatch + 1024);   // [GCAP*64] LDS P window (POOL)
  const int tid = threadIdx.x;
  const int ch = (bid >= halfg) ? 1 : 0;    // column half: cols ch*64..+63
  const int t0 = bid - ch * halfg;          // pair (b, b+halfg): same XCD
  for (int i = tid; i < 64 * KM; i += 256) {
    const int n = i / KM, kb = i % KM;
    const int kb2 = kb ^ (n & (KM - 1));
    const int gsrc = ((ch * 64 + n) * KM + kb) * 8;
    *(uint4*)(&lds[(n * KM + kb2) * 8])          = *(const uint4*)(BhiT + gsrc);
    *(uint4*)(&lds[64 * K + (n * KM + kb2) * 8]) = *(const uint4*)(BloT + gsrc);
  }
  if (tid < 64) { sred[tid] = 0.f; qred[tid] = 0.f; }
  const int nmt = (M + 127) >> 7;           // 128-row macro tiles (M % 64 == 0)
  int mt_begin, mt_end, mt_step, rlo = 0;
  if (POOL) {
    const int qt = nmt / halfg, rm = nmt % halfg;
    mt_begin = (t0 < rm) ? t0 * (qt + 1) : rm * (qt + 1) + (t0 - rm) * qt;
    mt_end   = mt_begin + ((t0 < rm) ? qt + 1 : qt);
    mt_step  = 1;
    rlo = mt_begin << 7;
    const int rcnt = min(mt_end << 7, M) - rlo;   // <= 1024 (max 7 tiles/block)
    for (int i = tid; i < rcnt; i += 256) sbatch[i] = (u16)batch[rlo + i];
    for (int i = tid; i < GCAP * 64; i += 256) Pacc[i] = 0.f;
  } else {
    mt_begin = t0; mt_end = nmt; mt_step = halfg;
  }
  __syncthreads();
  const int g_lo = POOL ? (int)sbatch[0] : 0;     // wave-uniform broadcast read
  const int wid = tid >> 6, lane = tid & 63, q = lane >> 4, r16 = lane & 15;
  float ls[4], lq[4];
#pragma unroll
  for (int nb = 0; nb < 4; nb++) { ls[nb] = 0.f; lq[nb] = 0.f; }
  float bv[4];
#pragma unroll
  for (int nb = 0; nb < 4; nb++) bv[nb] = HASBIAS ? bias[ch * 64 + nb * 16 + r16] : 0.f;

  for (int mt = mt_begin; mt < mt_end; mt += mt_step) {
    const int row0 = mt << 7;               // rt=0 rows always valid
    const bool ok1 = (row0 + 64) < M;       // rt=1 rows row0+64..127

    bf16x8 av[2][KR];
    if (AF32) {
      const float* Af = (const float*)Av + (size_t)(row0 + (wid << 4) + r16) * K + q * 8;
#pragma unroll
      for (int kk = 0; kk < KR; kk++) {
        f32x4 x0 = *(const f32x4*)(Af + kk * 32);
        f32x4 x1 = *(const f32x4*)(Af + kk * 32 + 4);
#pragma unroll
        for (int j = 0; j < 4; j++) { av[0][kk][j] = (__bf16)x0[j]; av[0][kk][4 + j] = (__bf16)x1[j]; }
      }
      if (ok1) {
        const float* Ag = Af + (size_t)64 * K;
#pragma unroll
        for (int kk = 0; kk < KR; kk++) {
          f32x4 x0 = *(const f32x4*)(Ag + kk * 32);
          f32x4 x1 = *(const f32x4*)(Ag + kk * 32 + 4);
#pragma unroll
          for (int j = 0; j < 4; j++) { av[1][kk][j] = (__bf16)x0[j]; av[1][kk][4 + j] = (__bf16)x1[j]; }
        }
      }
    } else {
      const u16* Ab = (const u16*)Av + (size_t)(row0 + (wid << 4) + r16) * K + q * 8;
#pragma unroll
      for (int kk = 0; kk < KR; kk++) av[0][kk] = *(const bf16x8*)(Ab + kk * 32);
      if (ok1) {
#pragma unroll
        for (int kk = 0; kk < KR; kk++) av[1][kk] = *(const bf16x8*)(Ab + (size_t)64 * K + kk * 32);
      }
    }

    f32x4 acc[2][4];
#pragma unroll
    for (int rt = 0; rt < 2; rt++)
#pragma unroll
      for (int nb = 0; nb < 4; nb++) acc[rt][nb] = (f32x4){0.f, 0.f, 0.f, 0.f};
#pragma unroll
    for (int kk = 0; kk < KR; kk++) {
#pragma unroll
      for (int nb = 0; nb < 4; nb++) {
        const int n = nb * 16 + r16;
        const int kb2 = (kk * 4 + q) ^ (n & (KM - 1));
        const bf16x8 bh = *(const bf16x8*)(&lds[(n * KM + kb2) * 8]);
        const bf16x8 bl = *(const bf16x8*)(&lds[64 * K + (n * KM + kb2) * 8]);
        acc[0][nb] = __builtin_amdgcn_mfma_f32_16x16x32_bf16(av[0][kk], bh, acc[0][nb], 0, 0, 0);
        acc[0][nb] = __builtin_amdgcn_mfma_f32_16x16x32_bf16(av[0][kk], bl, acc[0][nb], 0, 0, 0);
        if (ok1) {
          acc[1][nb] = __builtin_amdgcn_mfma_f32_16x16x32_bf16(av[1][kk], bh, acc[1][nb], 0, 0, 0);
          acc[1][nb] = __builtin_amdgcn_mfma_f32_16x16x32_bf16(av[1][kk], bl, acc[1][nb], 0, 0, 0);
        }
      }
    }

#pragma unroll
    for (int rt = 0; rt < 2; rt++) {
      if (rt && !ok1) continue;
      const int rbase = row0 + rt * 64 + (wid << 4) + (q << 2);
#pragma unroll
      for (int nb = 0; nb < 4; nb++) {
        const int col = ch * 64 + nb * 16 + r16;
#pragma unroll
        for (int r = 0; r < 4; r++) {
          float v = acc[rt][nb][r] + bv[nb];
          if (RELU) v = fmaxf(v, 0.f);
          ls[nb] += v; lq[nb] += v * v;
          if (!POOL) C[(size_t)(rbase + r) * 128 + col] = f2b(v);
          else acc[rt][nb][r] = v;
        }
      }
      if (POOL) {
        int bg[4];
#pragma unroll
        for (int r = 0; r < 4; r++) bg[r] = (int)sbatch[rbase - rlo + r];   // LDS, no vmcnt
        const int g0 = __shfl(bg[0], 0, 64);    // batch[first row of wave tile]
        const int g1 = __shfl(bg[3], 48, 64);   // batch[last row of wave tile]
        for (int g = g0; g <= g1; ++g) {        // wave-uniform, almost always 1 iter
#pragma unroll
          for (int nb = 0; nb < 4; nb++) {
            float sv = 0.f;
#pragma unroll
            for (int r = 0; r < 4; r++) sv += (bg[r] == g) ? acc[rt][nb][r] : 0.f;
            sv += __shfl_xor(sv, 16, 64);       // sum the 4 q-groups (16 rows)
            sv += __shfl_xor(sv, 32, 64);
            if (q == 0) {
              const int gi = g - g_lo;          // wave-uniform branch
              if ((unsigned)gi < GCAP) atomicAdd(&Pacc[gi * 64 + nb * 16 + r16], sv);
              else atomicAdd(&P[g * 128 + ch * 64 + nb * 16 + r16], sv);
            }
          }
        }
      }
    }
  }
#pragma unroll
  for (int nb = 0; nb < 4; nb++) {
    atomicAdd(&sred[nb * 16 + r16], ls[nb]);
    atomicAdd(&qred[nb * 16 + r16], lq[nb]);
  }
  __syncthreads();
  if (tid < 64) {
    atomicAdd(&stats[ch * 64 + tid], sred[tid]);
    atomicAdd(&stats[128 + ch * 64 + tid], qred[tid]);
  }
  if (POOL) {
    // one flush per block; zero entries skipped (RELU values nonneg -> exact)
    for (int i = tid; i < GCAP * 64; i += 256) {
      const float v = Pacc[i];
      if (v != 0.f) atomicAdd(&P[(g_lo + (i >> 6)) * 128 + ch * 64 + (i & 63)], v);
    }
  }
}

template<int K, bool RELU, bool HASBIAS, bool AF32, bool POOL>
__global__ __launch_bounds__(256) void k_gemm(const void* __restrict__ Av,
                                              const u16* __restrict__ BhiT,
                                              const u16* __restrict__ BloT,
                                              const float* __restrict__ bias,
                                              u16* __restrict__ C,
                                              float* __restrict__ stats,
                                              const int* __restrict__ batch,
                                              float* __restrict__ P, int M)
{
  gemm_body<K, RELU, HASBIAS, AF32, POOL>(Av, BhiT, BloT, bias, C, stats, batch, P, M,
                                          blockIdx.x, gridDim.x >> 1);
}

// ---- fused dispatch: blocks [0,g1blk) = K=128 POOL GEMM (h0 -> P1),
//      blocks [g1blk, g1blk+g2blk) = K=32 POOL GEMM (act -> P2). ----
__global__ __launch_bounds__(256) void k_gemm2(const void* __restrict__ A1,
                                               const u16* __restrict__ B1hi,
                                               const u16* __restrict__ B1lo,
                                               const float* __restrict__ bias1,
                                               float* __restrict__ stats1,
                                               float* __restrict__ P1,
                                               const void* __restrict__ A2,
                                               const u16* __restrict__ B2hi,
                                               const u16* __restrict__ B2lo,
                                               const float* __restrict__ bias2,
                                               float* __restrict__ stats2,
                                               float* __restrict__ P2,
                                               const int* __restrict__ batch,
                                               int M, int g1blk, int g2blk)
{
  if ((int)blockIdx.x < g1blk)
    gemm_body<128, true, true, false, true>(A1, B1hi, B1lo, bias1, nullptr, stats1,
                                            batch, P1, M, blockIdx.x, g1blk >> 1);
  else
    gemm_body<32, true, true, true, true>(A2, B2hi, B2lo, bias2, nullptr, stats2,
                                          batch, P2, M, blockIdx.x - g1blk, g2blk >> 1);
}

// ---- prep0: blocks [0,NZ) zero scratch; [NZ,NZ+48) split Wg/W2 hi/lo T; rest: bounds ----
__global__ void k_prep0(const float* __restrict__ Wg, const float* __restrict__ W2,
                        u16* __restrict__ WghiT, u16* __restrict__ WgloT,
                        u16* __restrict__ W2hiT, u16* __restrict__ W2loT,
                        const int* __restrict__ batch, int* __restrict__ gofs,
                        int* __restrict__ zbase, int zwords, int NZ, int N, int B)
{
  const int bid = blockIdx.x, t = threadIdx.x;
  if (bid < NZ) {
    const int i = bid * 2048 + t * 8;       // zwords padded to multiple of 8
    if (i < zwords) {
      *(int4*)(zbase + i)     = make_int4(0, 0, 0, 0);
      *(int4*)(zbase + i + 4) = make_int4(0, 0, 0, 0);
    }
  } else if (bid < NZ + 48) {
    const int i = (bid - NZ) * 256 + t;
    if (i < 64 * 128) {
      int k = i >> 7, n = i & 127;
      float w = Wg[i]; u16 h = f2b(w);
      WghiT[n * 64 + k] = h; WgloT[n * 64 + k] = f2b(w - b2f(h));
    } else if (i < 64 * 128 + 32 * 128) {
      int j = i - 64 * 128;
      int k = j >> 7, n = j & 127;
      float w = W2[j]; u16 h = f2b(w);
      W2hiT[n * 32 + k] = h; W2loT[n * 32 + k] = f2b(w - b2f(h));
    }
  } else {
    const int i = (bid - NZ - 48) * 256 + t;
    if (i == 0) { for (int g = 0; g <= batch[0]; g++) gofs[g] = 0; }
    if (i == N - 1) { for (int g = batch[N - 1] + 1; g <= B; g++) gofs[g] = N; }
    if (i < N - 1) {
      const int b0 = batch[i], b1 = batch[i + 1];
      for (int g = b0 + 1; g <= b1; g++) gofs[g] = i + 1;
    }
  }
}

// ========== binned edge partition ==========
__global__ __launch_bounds__(256) void k_bincnt(const int* __restrict__ dst, int* __restrict__ btot,
                                                int E, int NB)
{
  extern __shared__ int hist[];
  const int tid = threadIdx.x;
  for (int i = tid; i < NB; i += 256) hist[i] = 0;
  __syncthreads();
  const int chunk = (E + gridDim.x - 1) / gridDim.x;
  const int start = blockIdx.x * chunk;
  const int end = min(start + chunk, E);
  for (int e = start + tid; e < end; e += 256) atomicAdd(&hist[((u32)dst[e]) >> BSHIFT], 1);
  __syncthreads();
  for (int i = tid; i < NB; i += 256) if (hist[i]) atomicAdd(&btot[i], hist[i]);
}

// single-block exclusive scan; out[0..n-1] = exclusive, out[n] = total
__global__ void k_exscan(const int* __restrict__ in, int* __restrict__ out, int n)
{
  __shared__ int s[256];
  const int t = threadIdx.x;
  const int per = (n + 255) / 256;
  const int base = t * per;
  int loc[8]; int sum = 0;
  for (int j = 0; j < per; j++) { int v = (base + j < n) ? in[base + j] : 0; loc[j] = sum; sum += v; }
  s[t] = sum; __syncthreads();
  for (int o = 1; o < 256; o <<= 1) {
    int x = (t >= o) ? s[t - o] : 0;
    __syncthreads();
    s[t] += x;
    __syncthreads();
  }
  const int ex = s[t] - sum;
  for (int j = 0; j < per; j++) if (base + j < n) out[base + j] = ex + loc[j];
  if (t == 255) out[n] = s[255];
}

// re-read edges, reserve per-(block,bucket) ranges, stream (dst,src) pairs
__global__ __launch_bounds__(256) void k_bin(const int* __restrict__ src, const int* __restrict__ dst,
                                             const int* __restrict__ bbase, int* __restrict__ bcur,
                                             uint2* __restrict__ pairs, int E, int NB)
{
  extern __shared__ int lds[];
  int* hist = lds; int* wbase = lds + NB;
  const int tid = threadIdx.x;
  for (int i = tid; i < NB; i += 256) hist[i] = 0;
  __syncthreads();
  const int chunk = (E + gridDim.x - 1) / gridDim.x;
  const int start = blockIdx.x * chunk;
  const int end = min(start + chunk, E);
  for (int e = start + tid; e < end; e += 256) atomicAdd(&hist[((u32)dst[e]) >> BSHIFT], 1);
  __syncthreads();
  for (int i = tid; i < NB; i += 256) {
    int c = hist[i];
    wbase[i] = c ? bbase[i] + atomicAdd(&bcur[i], c) : 0;
    hist[i] = 0;
  }
  __syncthreads();
  for (int e = start + tid; e < end; e += 256) {
    const int d = dst[e];
    const int b = ((u32)d) >> BSHIFT;
    const int o = atomicAdd(&hist[b], 1);
    pairs[wbase[b] + o] = make_uint2((u32)d, (u32)src[e]);
  }
}

// ---- per-bucket: degree hist -> LDS scan -> offsets/dinv/self-loop -> scatter ----
// Also fused: y[i] = bf16(x[i] * dinv[i]) for the bucket's own 512 nodes (coalesced).
__global__ __launch_bounds__(256) void k_bucket(const uint2* __restrict__ pairs,
                                                const int* __restrict__ bbase,
                                                const float* __restrict__ x,
                                                int* __restrict__ offsets, float* __restrict__ dinv,
                                                int* __restrict__ elist, u16* __restrict__ y,
                                                int N, int NB, int Etot)
{
  __shared__ int hist[512];
  __shared__ int scan[256];
  __shared__ int lcur[512];
  __shared__ float sdinv[512];
  const int b = blockIdx.x, t = threadIdx.x;
  const int nbase = b << BSHIFT;
  const int nn = min(1 << BSHIFT, N - nbase);
  hist[t] = 0; hist[256 + t] = 0;
  __syncthreads();
  const int p0 = bbase[b], p1 = bbase[b + 1];
  for (int p = p0 + t; p < p1; p += 256) atomicAdd(&hist[pairs[p].x - nbase], 1);
  __syncthreads();
  const int h0 = hist[2 * t], h1 = hist[2 * t + 1];
  const int psum = h0 + h1;
  scan[t] = psum; __syncthreads();
  for (int o = 1; o < 256; o <<= 1) {
    int xx = (t >= o) ? scan[t - o] : 0;
    __syncthreads();
    scan[t] += xx;
    __syncthreads();
  }
  const int ex = scan[t] - psum;   // edges in this bucket before node 2t
  const int li0 = 2 * t, li1 = 2 * t + 1;
  if (li0 < nn) {
    const int i = nbase + li0;
    const int off = p0 + ex + i;
    const float d = rsqrtf((float)(h0 + 1));
    offsets[i] = off; elist[off] = i; lcur[li0] = off + 1;
    dinv[i] = d; sdinv[li0] = d;
  }
  if (li1 < nn) {
    const int i = nbase + li1;
    const int off = p0 + ex + h0 + i;
    const float d = rsqrtf((float)(h1 + 1));
    offsets[i] = off; elist[off] = i; lcur[li1] = off + 1;
    dinv[i] = d; sdinv[li1] = d;
  }
  if (b == NB - 1 && t == 0) offsets[N] = Etot;
  __syncthreads();
  for (int p = p0 + t; p < p1; p += 256) {
    const uint2 pr = pairs[p];
    const int pos = atomicAdd(&lcur[pr.x - nbase], 1);
    elist[pos] = (int)pr.y;
  }
  // fused cast: y rows for this bucket (sdinv visible via the sync above)
  const size_t ebase = (size_t)nbase * 64;
  const int total = nn * 64;
  for (int i = t * 8; i < total; i += 256 * 8) {
    const float d = sdinv[i >> 6];
    f32x4 a = *(const f32x4*)(x + ebase + i);
    f32x4 c = *(const f32x4*)(x + ebase + i + 4);
    u16 o[8];
#pragma unroll
    for (int j = 0; j < 4; j++) { o[j] = f2b(a[j] * d); o[4 + j] = f2b(c[j] * d); }
    *(uint4*)(y + ebase + i) = *(uint4*)o;
  }
}

// ------- GCN aggregation: 2 nodes/wave (half-wave each), 4 groups x 8 lanes per node -------
// y premultiplied by dinv[src]; final scale by dinv[node]. ALL shfls wave-uniform
// (divergent __shfl on CDNA reads undefined data from EXEC-inactive lanes — r5/r6 bug).
__global__ __launch_bounds__(256) void k_agg(const u16* __restrict__ y, const int* __restrict__ offsets,
                                             const int* __restrict__ elist, const float* __restrict__ dinv,
                                             u16* __restrict__ aggx, int n)
{
  const int lane = threadIdx.x & 63;
  const int half = lane >> 5, l32 = lane & 31;
  const int g4 = l32 >> 3, sub = lane & 7;
  const int wid  = (blockIdx.x * 256 + threadIdx.x) >> 6;
  const int nw   = gridDim.x * 4;
  const int npair = (n + 1) >> 1;
  for (int pr = wid; pr < npair; pr += nw) {
    const int node = pr * 2 + half;          // n even -> node < n
    const int s0 = offsets[node], s1 = offsets[node + 1];
    const int mydeg = s1 - s0;
    const int degA = __shfl(mydeg, 0, 64);
    const int degB = __shfl(mydeg, 32, 64);
    const int degmax = max(degA, degB);
    float a[8];
#pragma unroll
    for (int t = 0; t < 8; t++) a[t] = 0.f;
    for (int base = 0; base < degmax; base += 32) {
      const int m = mydeg - base;            // may be <=0 for the finished half
      const int ev = (base + l32 < mydeg) ? elist[s0 + base + l32] : 0;
      const int iters = (min(32, degmax - base) + 3) >> 2;   // wave-uniform
      for (int it = 0; it < iters; it++) {
        const int j = it * 4 + g4;           // 0..31
        const int idx = __shfl(ev, half * 32 + j, 64);   // all lanes active
        if (j < m) {
          const uint4 v = *(const uint4*)(y + (size_t)idx * 64 + sub * 8);
          const u32 w[4] = {v.x, v.y, v.z, v.w};
#pragma unroll
          for (int t = 0; t < 4; t++) {
            a[2 * t]     += b2f((u16)w[t]);
            a[2 * t + 1] += b2f((u16)(w[t] >> 16));
          }
        }
      }
    }
#pragma unroll
    for (int t = 0; t < 8; t++) {
      a[t] += __shfl_xor(a[t], 8, 64);
      a[t] += __shfl_xor(a[t], 16, 64);
    }
    if (g4 == 0) {
      const float di = dinv[node];
      u16 o[8];
#pragma unroll
      for (int t = 0; t < 8; t++) o[t] = f2b(a[t] * di);
      *(uint4*)(aggx + (size_t)node * 64 + sub * 8) = *(uint4*)o;
    }
  }
}

// ---- fold BN0 into W1 (16 blocks x 8 k-rows): W1p = diag(a0)W1 hi/lo T, b1p = c0@W1+b1 ----
__global__ void k_prep1(const float* __restrict__ stats0, const float* __restrict__ W1,
                        const float* __restrict__ b1, const float* __restrict__ g0,
                        const float* __restrict__ be0, u16* __restrict__ W1hiT,
                        u16* __restrict__ W1loT, float* __restrict__ b1p, float n)
{
  __shared__ float A[8], Csh[8];
  const int t = threadIdx.x;  // 128 threads
  if (t < 8) {
    const int k = blockIdx.x * 8 + t;
    const float mu = stats0[k] / n;
    const float var = fmaxf(stats0[128 + k] / n - mu * mu, 0.f);
    const float a = g0[k] * rsqrtf(var + EPS);
    A[t] = a; Csh[t] = be0[k] - mu * a;
  }
  __syncthreads();
  float acc = (blockIdx.x == 0) ? b1[t] : 0.f;
#pragma unroll
  for (int kk = 0; kk < 8; kk++) {
    const int k = blockIdx.x * 8 + kk;
    const float w0 = W1[k * 128 + t];
    acc += Csh[kk] * w0;
    const float w = A[kk] * w0;
    const u16 h = f2b(w);
    W1hiT[t * 128 + k] = h;
    W1loT[t * 128 + k] = f2b(w - b2f(h));
  }
  atomicAdd(&b1p[t], acc);
}

// ---- merged BN1/BN2+W3 fold + per-graph head ----
__global__ void k_out3(const float* __restrict__ P1, const float* __restrict__ P2,
                       const int* __restrict__ gofs,
                       const float* __restrict__ stats1, const float* __restrict__ stats2,
                       const float* __restrict__ g1, const float* __restrict__ be1,
                       const float* __restrict__ g2, const float* __restrict__ be2,
                       const float* __restrict__ W3, const float* __restrict__ b3,
                       float* __restrict__ out, int B, float n)
{
  __shared__ float w1s[128], w2s[128], red[256], cS[2];
  const int t = threadIdx.x;  // 256 threads
  float c, wv;
  if (t < 128) {
    const float mu = stats1[t] / n;
    const float var = fmaxf(stats1[128 + t] / n - mu * mu, 0.f);
    const float a = g1[t] * rsqrtf(var + EPS);
    c = be1[t] - mu * a;
    wv = W3[t];
    w1s[t] = a * wv;
  } else {
    const int f = t - 128;
    const float mu = stats2[f] / n;
    const float var = fmaxf(stats2[128 + f] / n - mu * mu, 0.f);
    const float a = g2[f] * rsqrtf(var + EPS);
    c = be2[f] - mu * a;
    wv = W3[t];
    w2s[f] = a * wv;
  }
  red[t] = c * wv; __syncthreads();
  for (int o = 128; o; o >>= 1) { if (t < o) red[t] += red[t + o]; __syncthreads(); }
  if (t == 0) { cS[0] = red[0] + b3[0]; cS[1] = b3[0]; }
  __syncthreads();
  const int lane = t & 63;
  const int g = (blockIdx.x * 256 + t) >> 6;
  if (g >= B) return;
  const int cnt = gofs[g + 1] - gofs[g];
  const int k = 2 * lane;
  float d = P1[g * 128 + k] * w1s[k] + P1[g * 128 + k + 1] * w1s[k + 1]
          + P2[g * 128 + k] * w2s[k] + P2[g * 128 + k + 1] * w2s[k + 1];
#pragma unroll
  for (int o = 1; o < 64; o <<= 1) d += __shfl_xor(d, o, 64);
  if (lane == 0) out[g] = (cnt > 0) ? d / (float)cnt + cS[0] : cS[1];
}

extern "C" void kernel_launch(void* const* d_in, const int* in_sizes, int n_in,
                              void* d_out, int out_size, void* d_ws, size_t ws_size,
                              hipStream_t stream)
{
  const float* x    = (const float*)d_in[0];
  const float* act  = (const float*)d_in[1];
  const float* Wg   = (const float*)d_in[2];
  const float* bg   = (const float*)d_in[3];
  const float* g0   = (const float*)d_in[4];
  const float* be0  = (const float*)d_in[5];
  const float* W1   = (const float*)d_in[6];
  const float* b1   = (const float*)d_in[7];
  const float* g1   = (const float*)d_in[8];
  const float* be1  = (const float*)d_in[9];
  const float* W2   = (const float*)d_in[10];
  const float* b2   = (const float*)d_in[11];
  const float* g2   = (const float*)d_in[12];
  const float* be2  = (const float*)d_in[13];
  const float* W3   = (const float*)d_in[14];
  const float* b3   = (const float*)d_in[15];
  const int* eidx   = (const int*)d_in[16];
  const int* batch  = (const int*)d_in[17];

  const int N = in_sizes[17];          // 200000
  const int E = in_sizes[16] / 2;      // 1600000
  const int B = out_size;              // 1000
  const int* src = eidx;
  const int* dst = eidx + E;
  const int NB = (N + (1 << BSHIFT) - 1) >> BSHIFT;   // ~391 buckets

  char* ws = (char*)d_ws;
  size_t off = 0;
  auto alloc = [&](size_t bytes) -> char* {
    off = (off + 255) & ~(size_t)255;
    char* p = ws + off; off += bytes; return p;
  };

  u16* bufA = (u16*)alloc((size_t)N * 128 * 2);   // h0 (h1/h2 never materialized)
  u16* xb   = (u16*)alloc((size_t)N * 64 * 2);    // y (premult bf16 x)
  u16* aggx = (u16*)alloc((size_t)N * 64 * 2);

  int zwords = 768 + 128 + 2 * NB + 2 * 128 * B;  // stats+b1p+bins + P1+P2
  zwords = (zwords + 7) & ~7;                     // pad for int4-pair zeroing
  char* zbase   = alloc((size_t)zwords * 4);
  float* stats0 = (float*)zbase;
  float* stats1 = stats0 + 256;
  float* stats2 = stats1 + 256;
  float* b1p    = stats2 + 256;
  int*   btot   = (int*)(b1p + 128);
  int*   bcur   = btot + NB;
  float* P1     = (float*)(bcur + NB);            // [B,128] graph sums of h1
  float* P2     = P1 + 128 * B;                   // [B,128] graph sums of h2

  int*   offsets = (int*)alloc((size_t)(N + 1) * 4);
  float* dinv    = (float*)alloc((size_t)N * 4);
  int*   elist   = (int*)alloc((size_t)(E + N) * 4);
  uint2* pairs   = (uint2*)alloc((size_t)E * 8);
  int*   bbase   = (int*)alloc((size_t)(NB + 1) * 4);
  int*   gofs    = (int*)alloc((size_t)(B + 1) * 4);
  u16*   WghiT   = (u16*)alloc(128 * 64 * 2);
  u16*   WgloT   = (u16*)alloc(128 * 64 * 2);
  u16*   W1hiT   = (u16*)alloc(128 * 128 * 2);
  u16*   W1loT   = (u16*)alloc(128 * 128 * 2);
  u16*   W2hiT   = (u16*)alloc(128 * 32 * 2);
  u16*   W2loT   = (u16*)alloc(128 * 32 * 2);

  u16* h0 = bufA;

  // dynamic-LDS: B tiles (2*64*K u16 * 2) + sred/qred 512B + sbatch 2KB + Pacc 2KB
  const int smem64  = 2 * 64 * 64 * 2 + 512;                  // non-POOL
  const int smem128 = 2 * 64 * 128 * 2 + 512 + 2048 + 2048;   // 37376 B (fused max)

  // prep0: zero scratch (parallel, ~1 MB) + weight split + graph bounds
  const int NZ = (zwords + 2047) / 2048;          // 256 thr x 8 words per block
  const int nbounds = (N + 255) / 256;
  k_prep0<<<NZ + 48 + nbounds, 256, 0, stream>>>(Wg, W2, WghiT, WgloT, W2hiT, W2loT,
                                                 batch, gofs, (int*)zbase, zwords, NZ, N, B);
  // binned edge partition -> per-bucket CSR build + fused x->y cast
  k_bincnt<<<256, 256, NB * 4, stream>>>(dst, btot, E, NB);
  k_exscan<<<1, 256, 0, stream>>>(btot, bbase, NB);
  k_bin<<<256, 256, 2 * NB * 4, stream>>>(src, dst, bbase, bcur, pairs, E, NB);
  k_bucket<<<NB, 256, 0, stream>>>(pairs, bbase, x, offsets, dinv, elist, xb, N, NB, E + N);
  // aggregate, GEMM (+stats0) -> h0
  k_agg<<<2048, 256, 0, stream>>>(xb, offsets, elist, dinv, aggx, N);
  k_gemm<64, true, true, false, false><<<768, 256, smem64, stream>>>(aggx, WghiT, WgloT, bg,
                                                                     h0, stats0, nullptr, nullptr, N);
  // fold BN0 into W1
  k_prep1<<<16, 128, 0, stream>>>(stats0, W1, b1, g0, be0, W1hiT, W1loT, b1p, (float)N);
  // FUSED: h1-GEMM (K=128, h0 -> P1) overlapped with h2-GEMM (K=32, act -> P2)
  k_gemm2<<<768 + 512, 256, smem128, stream>>>(h0, W1hiT, W1loT, b1p, stats1, P1,
                                               act, W2hiT, W2loT, b2, stats2, P2,
                                               batch, N, 768, 512);
  // merged BN1/BN2+W3 fold + per-graph head
  k_out3<<<(B * 64 + 255) / 256, 256, 0, stream>>>(P1, P2, gofs, stats1, stats2,
                                                   g1, be1, g2, be2, W3, b3,
                                                   (float*)d_out, B, (float)N);
}